// Round 6
// baseline (5510.926 us; speedup 1.0000x reference)
//
#include <hip/hip_runtime.h>

// Problem constants
#define BB 2048
#define TT 26
#define DIN 512
#define HH 512
#define EE 256
#define CC 97
#define SS 32
#define G4 2048   // 4*H
#define XK2 1024  // gates GEMM K: ctx(512) + h(512)
#define NBLK 512  // persistent grid: 2 blocks/CU * 256 CUs (resource-guaranteed)

typedef unsigned short u16;
typedef __bf16 bf16x8 __attribute__((ext_vector_type(8)));
typedef float f32x4 __attribute__((ext_vector_type(4)));

__device__ __forceinline__ float bf2f(u16 u) {
    return __uint_as_float(((unsigned int)u) << 16);
}
__device__ __forceinline__ u16 f2bf(float f) {  // RNE
    unsigned int u = __float_as_uint(f);
    u = u + 0x7FFFu + ((u >> 16) & 1u);
    return (u16)(u >> 16);
}
__device__ __forceinline__ float th_f(float x) {
    return 1.0f - 2.0f * __builtin_amdgcn_rcpf(__expf(2.0f * x) + 1.0f);
}
__device__ __forceinline__ float sig_f(float x) {
    return __builtin_amdgcn_rcpf(1.0f + __expf(-x));
}
__device__ __forceinline__ void async16(const u16* g, u16* l) {
    __builtin_amdgcn_global_load_lds(
        (const __attribute__((address_space(1))) unsigned int*)(g),
        (__attribute__((address_space(3))) unsigned int*)(l), 16, 0, 0);
}

// Device-scope grid barrier: monotonic 2-level counters (8 x cacheline-spaced
// level-1 counters, one level-2 counter, one generation word).  Zeroed by
// prep_all every call.  Same release/acquire semantics as a kernel boundary.
__device__ __forceinline__ void gridbar(unsigned* sb, unsigned b, int bid) {
    __syncthreads();
    if (threadIdx.x == 0) {
        __threadfence();                         // release (L2 writeback)
        int c = bid & 7;
        unsigned p = atomicAdd(&sb[c * 32], 1u); // 64 blocks per class
        if (p == (b + 1) * 64 - 1) {
            unsigned q = atomicAdd(&sb[256], 1u);
            if (q == (b + 1) * 8 - 1)
                __hip_atomic_store(&sb[288], b + 1, __ATOMIC_RELEASE,
                                   __HIP_MEMORY_SCOPE_AGENT);
        }
        while (__hip_atomic_load(&sb[288], __ATOMIC_RELAXED,
                                 __HIP_MEMORY_SCOPE_AGENT) < b + 1)
            __builtin_amdgcn_s_sleep(2);
        __threadfence();                         // acquire (L1/L2 invalidate)
    }
    __syncthreads();
}

// ---------------------------------------------------------------------------
// Persistent mega-kernel: P-build + Hp + 32 x (attn | gates+LSTM | ph) + gen.
// 512 blocks x 256 threads, 2 blocks/CU (29.3 KB LDS, VGPR<=256 via bounds).
// ---------------------------------------------------------------------------
__global__ void __launch_bounds__(256, 2) persist(
    const u16* __restrict__ bH16, u16* __restrict__ Hp,
    u16* __restrict__ hid, u16* __restrict__ ctx,
    const u16* __restrict__ Wcat, const u16* __restrict__ Wce16,
    const u16* __restrict__ emb16, const u16* __restrict__ Wgen16,
    const u16* __restrict__ Wi2h16, const u16* __restrict__ Wh2h16,
    const float* __restrict__ bcat, float* __restrict__ P,
    float* __restrict__ ph, float* __restrict__ cst,
    const int* __restrict__ text, const float* __restrict__ wscore,
    const float* __restrict__ bh2h, const float* __restrict__ bgen,
    float* __restrict__ out, unsigned* __restrict__ sb)
{
    __shared__ __align__(16) union {
        struct { u16 As[64*32]; u16 Ws[128*32]; float gsm[64*68]; int txt[64]; } g;
        struct { u16 As[128*32]; u16 Ws[128*32]; } t;
        struct { u16 As[64*32]; u16 Ws[64*32]; } s;
    } sm;

    const int bid  = blockIdx.x;
    const int tid  = threadIdx.x;
    const int lane = tid & 63;
    const int wave = tid >> 6;
    const int srow = tid >> 2;
    const int scol = (tid & 3) * 8;
    const int fr   = lane & 15;
    const int fq   = lane >> 4;
    unsigned barix = 0;

    // hoisted w_score slice (constant across all 32 steps)
    float ws_r[8];
    {
        float4 w0 = *(const float4*)(wscore + lane * 8);
        float4 w1 = *(const float4*)(wscore + lane * 8 + 4);
        ws_r[0]=w0.x; ws_r[1]=w0.y; ws_r[2]=w0.z; ws_r[3]=w0.w;
        ws_r[4]=w1.x; ws_r[5]=w1.y; ws_r[6]=w1.z; ws_r[7]=w1.w;
    }

    // ======== prologue 1: P[128][2048] = emb16 @ Wce16^T  (bid < 64) ========
    if (bid < 64) {
        const int m0 = (bid >> 5) * 64;
        const int n0 = (bid & 31) * 64;
        const u16* Arow = emb16 + (size_t)(m0 + srow) * EE + scol;
        const u16* Wrow = Wce16 + (size_t)(n0 + srow) * EE + scol;
        u16* dA = sm.s.As + wave * 512;
        u16* dW = sm.s.Ws + wave * 512;
        const int wm = (wave >> 1) * 32, wn = (wave & 1) * 32;
        f32x4 acc[2][2];
        #pragma unroll
        for (int i = 0; i < 2; i++)
            #pragma unroll
            for (int j = 0; j < 2; j++)
                #pragma unroll
                for (int r = 0; r < 4; r++) acc[i][j][r] = 0.0f;
        for (int k0 = 0; k0 < EE; k0 += 32) {
            async16(Arow + k0, dA);
            async16(Wrow + k0, dW);
            __syncthreads();
            bf16x8 af[2], bw[2];
            #pragma unroll
            for (int i = 0; i < 2; i++)
                af[i] = *(const bf16x8*)&sm.s.As[(wm + i*16 + fr)*32 + fq*8];
            #pragma unroll
            for (int j = 0; j < 2; j++)
                bw[j] = *(const bf16x8*)&sm.s.Ws[(wn + j*16 + fr)*32 + fq*8];
            #pragma unroll
            for (int i = 0; i < 2; i++)
                #pragma unroll
                for (int j = 0; j < 2; j++)
                    acc[i][j] = __builtin_amdgcn_mfma_f32_16x16x32_bf16(
                        af[i], bw[j], acc[i][j], 0, 0, 0);
            __syncthreads();
        }
        #pragma unroll
        for (int j = 0; j < 2; j++) {
            int col = n0 + wn + j * 16 + fr;
            #pragma unroll
            for (int i = 0; i < 2; i++) {
                int row = m0 + wm + i * 16 + fq * 4;
                #pragma unroll
                for (int r = 0; r < 4; r++)
                    P[(size_t)(row + r) * G4 + col] = acc[i][j][r];
            }
        }
        __syncthreads();
    }

    // ======== prologue 2: Hp = bH16 @ Wi2h^T, 1664 128x128 tiles ========
    for (int tt = bid; tt < 1664; tt += NBLK) {
        const int n0 = (tt & 3) * 128;
        const int m0 = (tt >> 2) * 128;
        const u16* Arow0 = bH16 + (size_t)(m0 + srow) * DIN + scol;
        const u16* Arow1 = bH16 + (size_t)(m0 + 64 + srow) * DIN + scol;
        const u16* Wrow0 = Wi2h16 + (size_t)(n0 + srow) * DIN + scol;
        const u16* Wrow1 = Wi2h16 + (size_t)(n0 + 64 + srow) * DIN + scol;
        u16* dA0 = sm.t.As + wave * 512;
        u16* dA1 = sm.t.As + 2048 + wave * 512;
        u16* dW0 = sm.t.Ws + wave * 512;
        u16* dW1 = sm.t.Ws + 2048 + wave * 512;
        const int wm = (wave >> 1) * 64, wn = (wave & 1) * 64;
        f32x4 acc[4][4];
        #pragma unroll
        for (int i = 0; i < 4; i++)
            #pragma unroll
            for (int j = 0; j < 4; j++)
                #pragma unroll
                for (int r = 0; r < 4; r++) acc[i][j][r] = 0.0f;
        for (int k0 = 0; k0 < DIN; k0 += 32) {
            async16(Arow0 + k0, dA0);
            async16(Arow1 + k0, dA1);
            async16(Wrow0 + k0, dW0);
            async16(Wrow1 + k0, dW1);
            __syncthreads();
            bf16x8 af[4], bw[4];
            #pragma unroll
            for (int i = 0; i < 4; i++)
                af[i] = *(const bf16x8*)&sm.t.As[(wm + i*16 + fr)*32 + fq*8];
            #pragma unroll
            for (int j = 0; j < 4; j++)
                bw[j] = *(const bf16x8*)&sm.t.Ws[(wn + j*16 + fr)*32 + fq*8];
            #pragma unroll
            for (int i = 0; i < 4; i++)
                #pragma unroll
                for (int j = 0; j < 4; j++)
                    acc[i][j] = __builtin_amdgcn_mfma_f32_16x16x32_bf16(
                        af[i], bw[j], acc[i][j], 0, 0, 0);
            __syncthreads();
        }
        #pragma unroll
        for (int j = 0; j < 4; j++) {
            int col = n0 + wn + j * 16 + fr;
            #pragma unroll
            for (int i = 0; i < 4; i++) {
                int row = m0 + wm + i * 16 + fq * 4;
                #pragma unroll
                for (int r = 0; r < 4; r++)
                    Hp[(size_t)(row + r) * HH + col] = f2bf(acc[i][j][r]);
            }
        }
        __syncthreads();
    }

    gridbar(sb, barix++, bid);

    // ======================== the 32-step recurrence ========================
    for (int s = 0; s < SS; s++) {
        const u16* hprev = hid + (size_t)s * BB * HH;
        u16*       hnext = hid + (size_t)(s + 1) * BB * HH;

        // ---- attn: 1 wave = 1 batch row (wave-local, no LDS) ----
        {
            const int r = bid * 4 + wave;
            const float* phb = ph + (size_t)r * HH + lane * 8;
            float pr[8];
            float4 p0 = *(const float4*)phb;
            float4 p1 = *(const float4*)(phb + 4);
            pr[0]=p0.x; pr[1]=p0.y; pr[2]=p0.z; pr[3]=p0.w;
            pr[4]=p1.x; pr[5]=p1.y; pr[6]=p1.z; pr[7]=p1.w;

            float ev[TT];
            const u16* hpr = Hp + (size_t)r * TT * HH + lane * 8;
            #pragma unroll
            for (int t = 0; t < TT; t++) {
                uint4 hv = *(const uint4*)(hpr + t * HH);
                const u16* hu = (const u16*)&hv;
                float sum = 0.0f;
                #pragma unroll
                for (int j = 0; j < 8; j++)
                    sum += th_f(bf2f(hu[j]) + pr[j]) * ws_r[j];
                #pragma unroll
                for (int k = 1; k < 64; k <<= 1)
                    sum += __shfl_xor(sum, k);
                ev[t] = sum;
            }
            float mx = ev[0];
            #pragma unroll
            for (int t = 1; t < TT; t++) mx = fmaxf(mx, ev[t]);
            float ssum = 0.0f;
            #pragma unroll
            for (int t = 0; t < TT; t++) { ev[t] = __expf(ev[t] - mx); ssum += ev[t]; }
            float inv = 1.0f / ssum;

            float cx[8];
            #pragma unroll
            for (int j = 0; j < 8; j++) cx[j] = 0.0f;
            const u16* bb = bH16 + (size_t)r * TT * DIN + lane * 8;
            #pragma unroll
            for (int t = 0; t < TT; t++) {
                uint4 v = *(const uint4*)(bb + t * DIN);
                const u16* vu = (const u16*)&v;
                float a = ev[t] * inv;
                #pragma unroll
                for (int j = 0; j < 8; j++) cx[j] += a * bf2f(vu[j]);
            }
            u16 o[8];
            #pragma unroll
            for (int j = 0; j < 8; j++) o[j] = f2bf(cx[j]);
            *(uint4*)(ctx + (size_t)r * 512 + lane * 8) = *(const uint4*)o;
        }
        gridbar(sb, barix++, bid);

        // ---- gates + LSTM (64x128 tile, XCD swizzle) ----
        {
            int xcd = bid & 7, loc = bid >> 3;
            int by = (xcd & 3) * 8 + (loc & 7);     // 0..31
            int bx = (xcd >> 2) * 8 + (loc >> 3);   // 0..15
            const int m0 = by * 64;
            const int n0 = bx * 128;

            if (tid < 64) sm.g.txt[tid] = text[(m0 + tid) * SS + s];

            const u16* Actx  = ctx   + (size_t)(m0 + srow) * 512 + scol;
            const u16* Ahid  = hprev + (size_t)(m0 + srow) * 512 + scol;
            const u16* Wrow0 = Wcat + (size_t)(n0 + srow) * XK2 + scol;
            const u16* Wrow1 = Wcat + (size_t)(n0 + 64 + srow) * XK2 + scol;
            u16* dA  = sm.g.As + wave * 512;
            u16* dW0 = sm.g.Ws + wave * 512;
            u16* dW1 = sm.g.Ws + 2048 + wave * 512;

            const int wm = (wave & 1) * 32;
            const int wn = (wave >> 1) * 64;

            f32x4 acc[2][4];
            #pragma unroll
            for (int i = 0; i < 2; i++)
                #pragma unroll
                for (int j = 0; j < 4; j++)
                    #pragma unroll
                    for (int r = 0; r < 4; r++) acc[i][j][r] = 0.0f;

            #pragma unroll
            for (int k0 = 0; k0 < XK2; k0 += 32) {
                const u16* asrc = (k0 < 512) ? (Actx + k0) : (Ahid + (k0 - 512));
                async16(asrc, dA);
                async16(Wrow0 + k0, dW0);
                async16(Wrow1 + k0, dW1);
                __syncthreads();
                bf16x8 af[2], bw[4];
                #pragma unroll
                for (int i = 0; i < 2; i++)
                    af[i] = *(const bf16x8*)&sm.g.As[(wm + i*16 + fr)*32 + fq*8];
                #pragma unroll
                for (int j = 0; j < 4; j++)
                    bw[j] = *(const bf16x8*)&sm.g.Ws[(wn + j*16 + fr)*32 + fq*8];
                #pragma unroll
                for (int i = 0; i < 2; i++)
                    #pragma unroll
                    for (int j = 0; j < 4; j++)
                        acc[i][j] = __builtin_amdgcn_mfma_f32_16x16x32_bf16(
                            af[i], bw[j], acc[i][j], 0, 0, 0);
                __syncthreads();
            }

            #pragma unroll
            for (int p = 0; p < 2; p++) {
                if ((wave >> 1) == p) {
                    #pragma unroll
                    for (int j = 0; j < 4; j++) {
                        int cl = j * 16 + fr;
                        #pragma unroll
                        for (int i = 0; i < 2; i++) {
                            int rl = wm + i * 16 + fq * 4;
                            #pragma unroll
                            for (int r = 0; r < 4; r++)
                                sm.g.gsm[(rl + r) * 68 + cl] = acc[i][j][r];
                        }
                    }
                }
                __syncthreads();
                #pragma unroll
                for (int rr = 0; rr < 4; rr++) {
                    int idx = rr * 256 + tid;
                    int u = idx & 15, row = idx >> 4;
                    int base = row * 68 + 4 * u;
                    int hg = (n0 >> 2) + p * 16 + u;
                    int c0i = 4 * hg;
                    int ch = sm.g.txt[row];
                    float4 bc = *(const float4*)(bcat + c0i);
                    float4 pv = *(const float4*)(P + (size_t)ch * G4 + c0i);
                    float ig = sig_f(sm.g.gsm[base]     + bc.x + pv.x);
                    float fg = sig_f(sm.g.gsm[base + 1] + bc.y + pv.y);
                    float gg = th_f (sm.g.gsm[base + 2] + bc.z + pv.z);
                    float og = sig_f(sm.g.gsm[base + 3] + bc.w + pv.w);
                    size_t ci = (size_t)(m0 + row) * HH + hg;
                    float cn = fg * cst[ci] + ig * gg;
                    cst[ci] = cn;
                    hnext[(size_t)(m0 + row) * HH + hg] = f2bf(og * th_f(cn));
                }
                __syncthreads();
            }
        }
        gridbar(sb, barix++, bid);

        // ---- ph = h_{s+1} @ W_h2h^T + b_h2h  (bid < 256, 64x64 tiles) ----
        if (bid < 256) {
            const int n0 = (bid & 7) * 64;
            const int m0 = (bid >> 3) * 64;
            const u16* Arow = hnext  + (size_t)(m0 + srow) * HH + scol;
            const u16* Wrow = Wh2h16 + (size_t)(n0 + srow) * HH + scol;
            u16* dA = sm.s.As + wave * 512;
            u16* dW = sm.s.Ws + wave * 512;
            const int wm = (wave >> 1) * 32, wn = (wave & 1) * 32;
            f32x4 acc[2][2];
            #pragma unroll
            for (int i = 0; i < 2; i++)
                #pragma unroll
                for (int j = 0; j < 2; j++)
                    #pragma unroll
                    for (int r = 0; r < 4; r++) acc[i][j][r] = 0.0f;
            for (int k0 = 0; k0 < HH; k0 += 32) {
                async16(Arow + k0, dA);
                async16(Wrow + k0, dW);
                __syncthreads();
                bf16x8 af[2], bw[2];
                #pragma unroll
                for (int i = 0; i < 2; i++)
                    af[i] = *(const bf16x8*)&sm.s.As[(wm + i*16 + fr)*32 + fq*8];
                #pragma unroll
                for (int j = 0; j < 2; j++)
                    bw[j] = *(const bf16x8*)&sm.s.Ws[(wn + j*16 + fr)*32 + fq*8];
                #pragma unroll
                for (int i = 0; i < 2; i++)
                    #pragma unroll
                    for (int j = 0; j < 2; j++)
                        acc[i][j] = __builtin_amdgcn_mfma_f32_16x16x32_bf16(
                            af[i], bw[j], acc[i][j], 0, 0, 0);
                __syncthreads();
            }
            #pragma unroll
            for (int j = 0; j < 2; j++) {
                int col = n0 + wn + j * 16 + fr;
                float bv = bh2h[col];
                #pragma unroll
                for (int i = 0; i < 2; i++) {
                    int row = m0 + wm + i * 16 + fq * 4;
                    #pragma unroll
                    for (int r = 0; r < 4; r++)
                        ph[(size_t)(row + r) * HH + col] = acc[i][j][r] + bv;
                }
            }
        }
        gridbar(sb, barix++, bid);
    }

    // ======== epilogue: probs = hid[1..32] @ Wgen^T + b_gen ========
    {
        const int m0 = bid * 128;
        const u16* A = hid + (size_t)BB * HH;
        const u16* Arow0 = A + (size_t)(m0 + srow) * HH + scol;
        const u16* Arow1 = A + (size_t)(m0 + 64 + srow) * HH + scol;
        const u16* Wrow0 = Wgen16 + (size_t)srow * HH + scol;
        const u16* Wrow1 = Wgen16 + (size_t)(64 + srow) * HH + scol;
        u16* dA0 = sm.t.As + wave * 512;
        u16* dA1 = sm.t.As + 2048 + wave * 512;
        u16* dW0 = sm.t.Ws + wave * 512;
        u16* dW1 = sm.t.Ws + 2048 + wave * 512;
        const int wm = (wave >> 1) * 64, wn = (wave & 1) * 64;
        f32x4 acc[4][4];
        #pragma unroll
        for (int i = 0; i < 4; i++)
            #pragma unroll
            for (int j = 0; j < 4; j++)
                #pragma unroll
                for (int r = 0; r < 4; r++) acc[i][j][r] = 0.0f;
        for (int k0 = 0; k0 < HH; k0 += 32) {
            async16(Arow0 + k0, dA0);
            async16(Arow1 + k0, dA1);
            async16(Wrow0 + k0, dW0);
            async16(Wrow1 + k0, dW1);
            __syncthreads();
            bf16x8 af[4], bw[4];
            #pragma unroll
            for (int i = 0; i < 4; i++)
                af[i] = *(const bf16x8*)&sm.t.As[(wm + i*16 + fr)*32 + fq*8];
            #pragma unroll
            for (int j = 0; j < 4; j++)
                bw[j] = *(const bf16x8*)&sm.t.Ws[(wn + j*16 + fr)*32 + fq*8];
            #pragma unroll
            for (int i = 0; i < 4; i++)
                #pragma unroll
                for (int j = 0; j < 4; j++)
                    acc[i][j] = __builtin_amdgcn_mfma_f32_16x16x32_bf16(
                        af[i], bw[j], acc[i][j], 0, 0, 0);
            __syncthreads();
        }
        #pragma unroll
        for (int j = 0; j < 4; j++) {
            int col = wn + j * 16 + fr;
            if (col < CC) {
                float bv = bgen[col];
                #pragma unroll
                for (int i = 0; i < 4; i++) {
                    int row = m0 + wm + i * 16 + fq * 4;
                    #pragma unroll
                    for (int r = 0; r < 4; r++) {
                        int m = row + r;
                        int ss = m >> 11, b = m & (BB - 1);
                        out[(size_t)b * (SS * CC) + ss * CC + col] =
                            acc[i][j][r] + bv;
                    }
                }
            }
        }
    }
}

// ---------------------------------------------------------------------------
// prep kernels
// ---------------------------------------------------------------------------
__global__ __launch_bounds__(256) void cast_f32_bf16(
    const float* __restrict__ src, u16* __restrict__ dst, int n)
{
    int i = (blockIdx.x * 256 + threadIdx.x) * 4;
    if (i < n) {
        float4 v = *(const float4*)(src + i);
        ushort4 o;
        o.x = f2bf(v.x); o.y = f2bf(v.y); o.z = f2bf(v.z); o.w = f2bf(v.w);
        *(ushort4*)(dst + i) = o;
    }
}

__global__ __launch_bounds__(256) void prep_all(
    const float* __restrict__ W_ih, const float* __restrict__ W_hh,
    const float* __restrict__ b_ih, const float* __restrict__ b_hh,
    const float* __restrict__ b_h2h, const float* __restrict__ emb,
    const float* __restrict__ W_i2h, const float* __restrict__ W_h2h,
    const float* __restrict__ W_gen,
    u16* __restrict__ Wcat, u16* __restrict__ Wce16, u16* __restrict__ emb16,
    u16* __restrict__ Wgen16, u16* __restrict__ Wi2h16, u16* __restrict__ Wh2h16,
    float* __restrict__ bcat, float* __restrict__ cst, u16* __restrict__ hid0,
    float* __restrict__ ph, unsigned* __restrict__ sb)
{
    int i = blockIdx.x * 256 + threadIdx.x;   // grid covers 2,097,152

    // Wcat [2048][1024] interleaved row np=4h+g: [W_ih[:, :512] | W_hh]
    {
        int np = i >> 10, k = i & (XK2 - 1);
        int h = np >> 2, g = np & 3;
        int n = g * HH + h;
        float v = (k < 512) ? W_ih[(size_t)n * (DIN + EE) + k]
                            : W_hh[(size_t)n * HH + (k - 512)];
        Wcat[(size_t)i] = f2bf(v);
    }
    if (i < G4 * EE) {   // Wce16 [2048][256] interleaved: W_ih[:, 512:768]
        int np = i >> 8, e = i & (EE - 1);
        int h = np >> 2, g = np & 3;
        int n = g * HH + h;
        Wce16[i] = f2bf(W_ih[(size_t)n * (DIN + EE) + DIN + e]);
    }
    if (i < 128 * EE) {  // emb16 [128][256], rows >= 97 zeroed
        int ch = i >> 8, e = i & (EE - 1);
        emb16[i] = (ch < CC) ? f2bf(emb[(size_t)ch * EE + e]) : (u16)0;
    }
    if (i < 128 * HH) {  // Wgen16 [128][512], rows >= 97 zeroed
        int n = i >> 9, k = i & (HH - 1);
        Wgen16[i] = (n < CC) ? f2bf(W_gen[(size_t)n * HH + k]) : (u16)0;
    }
    if (i < HH * DIN) Wi2h16[i] = f2bf(W_i2h[i]);
    if (i < HH * HH)  Wh2h16[i] = f2bf(W_h2h[i]);
    if (i < G4) {        // bcat interleaved
        int h = i >> 2, g = i & 3;
        int n = g * HH + h;
        bcat[i] = b_ih[n] + b_hh[n];
    }
    if (i < BB * HH) {   // state init: c=0, hid slot0 = 0, ph = b_h2h
        cst[i] = 0.0f;
        hid0[i] = 0;
        ph[i] = b_h2h[i & (HH - 1)];
    }
    if (i < 320) sb[i] = 0;   // grid-barrier counters
}

// ---------------------------------------------------------------------------
// Workspace layout (bytes)  — total ~196 MB (ws ~436 MB available)
// ---------------------------------------------------------------------------
#define BH16_OFF  ((size_t)0)             // bf16 [B*T, DIN]   54,525,952
#define HP_OFF    ((size_t)54525952)      // bf16 [B*T, H]     54,525,952
#define HID_OFF   ((size_t)109051904)     // bf16 [33][B][H]   69,206,016
#define CTX_OFF   ((size_t)178257920)     // bf16 [B][512]      2,097,152
#define WCAT_OFF  ((size_t)180355072)     // bf16 [2048][1024]  4,194,304
#define WCE_OFF   ((size_t)184549376)     // bf16 [2048][256]   1,048,576
#define EMB16_OFF ((size_t)185597952)     // bf16 [128][256]       65,536
#define WGEN_OFF  ((size_t)185663488)     // bf16 [128][512]      131,072
#define WI2H_OFF  ((size_t)185794560)     // bf16 [512][512]      524,288
#define WH2H_OFF  ((size_t)186318848)     // bf16 [512][512]      524,288
#define BCAT_OFF  ((size_t)186843136)     // f32 [2048]             8,192
#define P_OFF     ((size_t)186851328)     // f32 [128][2048]    1,048,576
#define PH_OFF    ((size_t)187899904)     // f32 [B][512]       4,194,304
#define CST_OFF   ((size_t)192094208)     // f32 [B][512]       4,194,304
#define SYNC_OFF  ((size_t)196288512)     // u32 [320]              1,280

extern "C" void kernel_launch(void* const* d_in, const int* in_sizes, int n_in,
                              void* d_out, int out_size, void* d_ws, size_t ws_size,
                              hipStream_t stream)
{
    const float* batch_H = (const float*)d_in[0];
    const int*   text    = (const int*)d_in[1];
    const float* W_i2h   = (const float*)d_in[2];
    const float* W_h2h   = (const float*)d_in[3];
    const float* b_h2h   = (const float*)d_in[4];
    const float* w_score = (const float*)d_in[5];
    const float* W_ih    = (const float*)d_in[6];
    const float* W_hh    = (const float*)d_in[7];
    const float* b_ih    = (const float*)d_in[8];
    const float* b_hh    = (const float*)d_in[9];
    const float* W_gen   = (const float*)d_in[10];
    const float* b_gen   = (const float*)d_in[11];
    const float* emb     = (const float*)d_in[12];

    char* ws = (char*)d_ws;
    u16*   bH16   = (u16*)(ws + BH16_OFF);
    u16*   Hp     = (u16*)(ws + HP_OFF);
    u16*   hid    = (u16*)(ws + HID_OFF);
    u16*   ctx    = (u16*)(ws + CTX_OFF);
    u16*   Wcat   = (u16*)(ws + WCAT_OFF);
    u16*   Wce16  = (u16*)(ws + WCE_OFF);
    u16*   emb16  = (u16*)(ws + EMB16_OFF);
    u16*   Wgen16 = (u16*)(ws + WGEN_OFF);
    u16*   Wi2h16 = (u16*)(ws + WI2H_OFF);
    u16*   Wh2h16 = (u16*)(ws + WH2H_OFF);
    float* bcat   = (float*)(ws + BCAT_OFF);
    float* P      = (float*)(ws + P_OFF);
    float* ph     = (float*)(ws + PH_OFF);
    float* cst    = (float*)(ws + CST_OFF);
    unsigned* sb  = (unsigned*)(ws + SYNC_OFF);
    float* out    = (float*)d_out;

    cast_f32_bf16<<<dim3((BB * TT * DIN / 4) / 256), 256, 0, stream>>>(
        batch_H, bH16, BB * TT * DIN);
    prep_all<<<dim3((G4 * XK2) / 256), 256, 0, stream>>>(
        W_ih, W_hh, b_ih, b_hh, b_h2h, emb, W_i2h, W_h2h, W_gen,
        Wcat, Wce16, emb16, Wgen16, Wi2h16, Wh2h16, bcat, cst, hid, ph, sb);

    persist<<<dim3(NBLK), 256, 0, stream>>>(
        bH16, Hp, hid, ctx, Wcat, Wce16, emb16, Wgen16, Wi2h16, Wh2h16,
        bcat, P, ph, cst, text, w_score, b_h2h, b_gen, out, sb);
}